// Round 7
// baseline (265.769 us; speedup 1.0000x reference)
//
#include <hip/hip_runtime.h>
#include <stdint.h>
#include <float.h>

#define TOTAL 16368
#define KSEL 500

// order-preserving float<->uint key (monotonic increasing on finite floats)
__device__ __forceinline__ uint32_t fkey(float f) {
    uint32_t u = __float_as_uint(f);
    return (u & 0x80000000u) ? ~u : (u | 0x80000000u);
}
__device__ __forceinline__ float keyf(uint32_t k) {
    uint32_t u = (k & 0x80000000u) ? (k & 0x7FFFFFFFu) : ~k;
    return __uint_as_float(u);
}
__device__ __forceinline__ int wave_sumi(int v) {
    #pragma unroll
    for (int o = 32; o > 0; o >>= 1) v += __shfl_xor(v, o, 64);
    return v;
}
__device__ __forceinline__ float wave_sumf(float v) {
    #pragma unroll
    for (int o = 32; o > 0; o >>= 1) v += __shfl_xor(v, o, 64);
    return v;
}
__device__ __forceinline__ float wave_maxf(float v) {
    #pragma unroll
    for (int o = 32; o > 0; o >>= 1) v = fmaxf(v, __shfl_xor(v, o, 64));
    return v;
}
__device__ __forceinline__ void lse_merge(float& m, float& l, float m2, float l2) {
    float M = fmaxf(m, m2);
    l = l * __expf(m - M) + l2 * __expf(m2 - M);
    m = M;
}

// Exact top-KSEL + KL for one group of C = NS*64 (>KSEL) elements.
// Entire group register-resident: NS u32 keys per lane, burst-loaded as float4
// (all NS/4 loads in flight at once -> max MLP). Bisection on key space with
// false-position; exact for arbitrary inputs (span collapse + index tie-break).
// PREF: prefetch ALL student values densely before bisection (for high
// selection density); else chunked predicated gather after selection.
// Returns kl on lane 0 (0 elsewhere).
template <int NS, bool PREF>
__device__ float group_topk(const float* __restrict__ t, const float* __restrict__ s) {
    const int lane = threadIdx.x & 63;
    constexpr int NC4 = NS / 4;
    const float4* t4 = (const float4*)t;

    float4 v[NC4];
    #pragma unroll
    for (int c = 0; c < NC4; ++c) v[c] = t4[lane + c * 64];   // all in flight

    float svp[PREF ? NS : 1];
    if (PREF) {
        const float4* s4 = (const float4*)s;
        #pragma unroll
        for (int c = 0; c < NC4; ++c) {
            float4 y = s4[lane + c * 64];
            svp[4 * c + 0] = y.x; svp[4 * c + 1] = y.y;
            svp[4 * c + 2] = y.z; svp[4 * c + 3] = y.w;
        }
    }

    uint32_t key[NS];
    #pragma unroll
    for (int c = 0; c < NC4; ++c) {
        key[4 * c + 0] = fkey(v[c].x); key[4 * c + 1] = fkey(v[c].y);
        key[4 * c + 2] = fkey(v[c].z); key[4 * c + 3] = fkey(v[c].w);
    }
    auto idxOf = [&](int j) { return ((lane + (j >> 2) * 64) << 2) + (j & 3); };

    uint32_t kmx = 0u, kmn = 0xFFFFFFFFu;
    #pragma unroll
    for (int j = 0; j < NS; ++j) {
        uint32_t k = key[j];
        kmx = k > kmx ? k : kmx;
        kmn = k < kmn ? k : kmn;
    }
    #pragma unroll
    for (int o = 32; o > 0; o >>= 1) {
        uint32_t a = __shfl_xor(kmx, o, 64); kmx = a > kmx ? a : kmx;
        uint32_t b = __shfl_xor(kmn, o, 64); kmn = b < kmn ? b : kmn;
    }
    const float tmax = keyf(kmx);

    // ---- bisection on u32 key space ----
    uint32_t lo = kmn - 1u, hi = kmx, tauhi = kmx;
    int cl = NS * 64, ch = 0, cut = -1;
    bool exact = false;
    for (int it = 0; it < 80; ++it) {
        uint32_t span = hi - lo;
        if (span <= 1u) break;
        uint32_t mid;
        if (!(it & 1)) {  // false position on empirical CDF
            uint64_t st = (uint64_t)span * (uint32_t)(cl - KSEL) / (uint32_t)(cl - ch);
            if (st < 1) st = 1;
            if (st > span - 1) st = span - 1;
            mid = lo + (uint32_t)st;
        } else mid = lo + (span >> 1);
        int c = 0;
        #pragma unroll
        for (int j = 0; j < NS; ++j) c += (key[j] > mid);
        c = wave_sumi(c);
        if (c == KSEL) { tauhi = mid; exact = true; break; }
        if (c > KSEL) { lo = mid; cl = c; } else { hi = mid; ch = c; }
    }
    if (!exact) {
        tauhi = hi;                       // tied elements have key == hi
        const int nT = KSEL - ch, nTie = cl - ch;
        if (nT >= nTie) cut = 0x7FFFFFFF;
        else {  // lowest-index tie-break via index bisection (rare)
            int l = -1, h = NS * 64 - 1;
            while (h - l > 1) {
                int m = (l + h) >> 1;
                int c = 0;
                #pragma unroll
                for (int j = 0; j < NS; ++j)
                    c += (key[j] == tauhi && idxOf(j) <= m);
                c = wave_sumi(c);
                if (c >= nT) h = m; else l = m;
            }
            cut = h;
        }
    }

    auto sel = [&](int j) {
        uint32_t kj = key[j];
        return (kj > tauhi) || (kj == tauhi && idxOf(j) <= cut);
    };

    // ---- accumulate KL pieces over the selected set ----
    float St = 0.f, Stt = 0.f, Sts = 0.f, sm = -FLT_MAX;
    if (PREF) {
        #pragma unroll
        for (int j = 0; j < NS; ++j) {
            if (sel(j)) {
                float tv = keyf(key[j]);
                float e = __expf(tv - tmax);
                St += e; Stt += e * tv; Sts += e * svp[j];
                sm = fmaxf(sm, svp[j]);
            }
        }
    } else {
        #pragma unroll
        for (int c0 = 0; c0 < NS; c0 += 16) {   // chunked predicated gather
            float sg[16];
            #pragma unroll
            for (int j2 = 0; j2 < 16; ++j2)
                sg[j2] = sel(c0 + j2) ? s[idxOf(c0 + j2)] : 0.f;
            #pragma unroll
            for (int j2 = 0; j2 < 16; ++j2) {
                int j = c0 + j2;
                if (sel(j)) {
                    float tv = keyf(key[j]);
                    float e = __expf(tv - tmax);
                    St += e; Stt += e * tv; Sts += e * sg[j2];
                    sm = fmaxf(sm, sg[j2]);
                }
            }
        }
    }
    #pragma unroll
    for (int o = 32; o > 0; o >>= 1) {
        St  += __shfl_xor(St,  o, 64);
        Stt += __shfl_xor(Stt, o, 64);
        Sts += __shfl_xor(Sts, o, 64);
        sm = fmaxf(sm, __shfl_xor(sm, o, 64));
    }
    float Ss = 0.f;
    if (PREF) {
        #pragma unroll
        for (int j = 0; j < NS; ++j)
            if (sel(j)) Ss += __expf(svp[j] - sm);
    } else {
        #pragma unroll
        for (int c0 = 0; c0 < NS; c0 += 16) {
            float sg[16];
            #pragma unroll
            for (int j2 = 0; j2 < 16; ++j2)
                sg[j2] = sel(c0 + j2) ? s[idxOf(c0 + j2)] : 0.f;
            #pragma unroll
            for (int j2 = 0; j2 < 16; ++j2)
                if (sel(c0 + j2)) Ss += __expf(sg[j2] - sm);
        }
    }
    Ss = wave_sumf(Ss);
    if (lane == 0)
        return (Stt - Sts) / St - tmax - __logf(St) + sm + __logf(Ss);
    return 0.f;
}

// tiny groups (k == C <= 256): whole-group softmax; returns kl on lane 0
__device__ float tiny_group(const float* __restrict__ t, const float* __restrict__ s,
                            int Cg) {
    const int lane = threadIdx.x & 63;
    float St = 0.f, Stt = 0.f, Sts = 0.f, m = -FLT_MAX, l = 0.f;
    float tv[4], svv[4];
    #pragma unroll
    for (int q = 0; q < 4; ++q) {
        int i = lane + q * 64;
        bool va = i < Cg;
        tv[q] = va ? t[i] : -FLT_MAX;
        svv[q] = va ? s[i] : 0.f;
    }
    float mx = -FLT_MAX;
    #pragma unroll
    for (int q = 0; q < 4; ++q) mx = fmaxf(mx, tv[q]);
    mx = wave_maxf(mx);
    #pragma unroll
    for (int q = 0; q < 4; ++q) {
        if (lane + q * 64 < Cg) {
            float e = __expf(tv[q] - mx);
            St += e; Stt += e * tv[q]; Sts += e * svv[q];
            float x = svv[q];
            if (x > m) { l = l * __expf(m - x) + 1.f; m = x; }
            else       { l += __expf(x - m); }
        }
    }
    #pragma unroll
    for (int o = 32; o > 0; o >>= 1) {
        St  += __shfl_xor(St,  o, 64);
        Stt += __shfl_xor(Stt, o, 64);
        Sts += __shfl_xor(Sts, o, 64);
        float m2 = __shfl_xor(m, o, 64);
        float l2 = __shfl_xor(l, o, 64);
        lse_merge(m, l, m2, l2);
    }
    if (lane == 0)
        return (Stt - Sts) / St - mx - __logf(St) + m + __logf(l);
    return 0.f;
}

__global__ __launch_bounds__(64, 2) void kd_all(const float* __restrict__ sL,
                                                const float* __restrict__ tL,
                                                float* __restrict__ out) {
    const int row = blockIdx.x;
    const int y = blockIdx.y;
    const float* tr = tL + (size_t)row * TOTAL;
    const float* sr = sL + (size_t)row * TOTAL;

    float kl = 0.f;
    switch (y) {
    case 0: kl = group_topk<128, false>(tr,         sr);         break;  // C=8192
    case 1: kl = group_topk<64,  false>(tr + 8192,  sr + 8192);  break;  // C=4096
    case 2:
        kl  = group_topk<32, true>(tr + 12288, sr + 12288);              // C=2048
        kl += group_topk<16, true>(tr + 14336, sr + 14336);              // C=1024
        break;
    default:
        kl  = group_topk<8, true>(tr + 15360, sr + 15360);               // C=512
        kl += tiny_group(tr + 15872, sr + 15872, 256);
        kl += tiny_group(tr + 16128, sr + 16128, 128);
        kl += tiny_group(tr + 16256, sr + 16256, 64);
        kl += tiny_group(tr + 16320, sr + 16320, 32);
        kl += tiny_group(tr + 16352, sr + 16352, 16);
        break;
    }
    if ((threadIdx.x & 63) == 0)
        atomicAdd(out, kl * (0.1f / 1024.f));
}

__global__ void zero_out_kernel(float* out) { out[0] = 0.f; }

extern "C" void kernel_launch(void* const* d_in, const int* in_sizes, int n_in,
                              void* d_out, int out_size, void* d_ws, size_t ws_size,
                              hipStream_t stream) {
    (void)in_sizes; (void)n_in; (void)d_ws; (void)ws_size; (void)out_size;
    const float* s = (const float*)d_in[0];
    const float* t = (const float*)d_in[1];
    float* out = (float*)d_out;

    hipLaunchKernelGGL(zero_out_kernel, dim3(1), dim3(1), 0, stream, out);
    hipLaunchKernelGGL(kd_all, dim3(1024, 4), dim3(64), 0, stream, s, t, out);
}

// Round 8
// 170.178 us; speedup vs baseline: 1.5617x; 1.5617x over previous
//
#include <hip/hip_runtime.h>
#include <stdint.h>
#include <float.h>

#define TOTAL 16368
#define KSEL 500
#define CAP 1280          // candidate cap per big group (mean ~1110, +5.5 sd)
#define NSLOT 20          // CAP / 64
#define NBUCKET 64

// order-preserving float<->uint key (monotonic increasing on finite floats)
__device__ __forceinline__ uint32_t fkey(float f) {
    uint32_t u = __float_as_uint(f);
    return (u & 0x80000000u) ? ~u : (u | 0x80000000u);
}
__device__ __forceinline__ float keyf(uint32_t k) {
    uint32_t u = (k & 0x80000000u) ? (k & 0x7FFFFFFFu) : ~k;
    return __uint_as_float(u);
}
__device__ __forceinline__ int wave_sumi(int v) {
    #pragma unroll
    for (int o = 32; o > 0; o >>= 1) v += __shfl_xor(v, o, 64);
    return v;
}
__device__ __forceinline__ float wave_sumf(float v) {
    #pragma unroll
    for (int o = 32; o > 0; o >>= 1) v += __shfl_xor(v, o, 64);
    return v;
}
__device__ __forceinline__ float wave_maxf(float v) {
    #pragma unroll
    for (int o = 32; o > 0; o >>= 1) v = fmaxf(v, __shfl_xor(v, o, 64));
    return v;
}
__device__ __forceinline__ void lse_merge(float& m, float& l, float m2, float l2) {
    float M = fmaxf(m, m2);
    l = l * __expf(m - M) + l2 * __expf(m2 - M);
    m = M;
}

// exact exhaustive fallback (never taken for N(0,1) bench data); returns kl on
// lane 0 (0 elsewhere). Bisection on 45-bit key (fkey<<13 | (8191-idx)).
__device__ __noinline__ float wave_slow_kl(const float* __restrict__ t,
                                           const float* __restrict__ s, int C) {
    const int lane = threadIdx.x & 63;
    uint64_t lo = 0ull, hi = (1ull << 45), tau = 0ull;
    int cl = C, ch = 0;
    for (int it = 0; it < 100; ++it) {
        uint64_t span = hi - lo;
        if (span <= 1ull) { tau = lo; break; }
        uint64_t mid;
        if (it & 1) mid = lo + (span >> 1);
        else {
            uint64_t st = span * (uint64_t)(cl - KSEL) / (uint64_t)(cl - ch);
            if (st < 1) st = 1;
            if (st > span - 1) st = span - 1;
            mid = lo + st;
        }
        int c = 0;
        for (int i = lane; i < C; i += 64) {
            uint64_t ck = ((uint64_t)fkey(t[i]) << 13) | (uint64_t)(8191 - i);
            c += (ck > mid);
        }
        c = wave_sumi(c);
        if (c == KSEL) { tau = mid; break; }
        if (c > KSEL) { lo = mid; cl = c; } else { hi = mid; ch = c; }
    }
    float tmx = -FLT_MAX;
    for (int i = lane; i < C; i += 64) tmx = fmaxf(tmx, t[i]);
    tmx = wave_maxf(tmx);
    float St = 0.f, Stt = 0.f, Sts = 0.f, sm = -FLT_MAX;
    for (int i = lane; i < C; i += 64) {
        float x = t[i];
        uint64_t ck = ((uint64_t)fkey(x) << 13) | (uint64_t)(8191 - i);
        if (ck > tau) {
            float e = __expf(x - tmx), v = s[i];
            St += e; Stt += e * x; Sts += e * v;
            sm = fmaxf(sm, v);
        }
    }
    St = wave_sumf(St); Stt = wave_sumf(Stt); Sts = wave_sumf(Sts); sm = wave_maxf(sm);
    float Ss = 0.f;
    for (int i = lane; i < C; i += 64) {
        uint64_t ck = ((uint64_t)fkey(t[i]) << 13) | (uint64_t)(8191 - i);
        if (ck > tau) Ss += __expf(s[i] - sm);
    }
    Ss = wave_sumf(Ss);
    if (lane == 0)
        return (Stt - Sts) / St - tmx - __logf(St) + sm + __logf(Ss);
    return 0.f;
}

// big groups (C = NF4*256): stream in 8-float4 bursts; scan-based order-free
// compaction (count -> wave exclusive scan -> per-lane scatter) to LDS; keys
// to regs; EARLY candidate student gather (outstanding across bisection);
// exact bisection + rare LDS-idx tie-break. Returns kl on lane 0.
template <int NF4>
__device__ float big_wave(const float* __restrict__ tg, const float* __restrict__ s,
                          float thr, float* vals, uint16_t* idxs) {
    const int lane = threadIdx.x & 63;
    const float4* t4 = (const float4*)tg;
    int cnt = 0;
    #pragma unroll
    for (int c0 = 0; c0 < NF4; c0 += 8) {
        float4 buf[8];
        #pragma unroll
        for (int u = 0; u < 8; ++u) buf[u] = t4[(c0 + u) * 64 + lane];
        int myc = 0;
        #pragma unroll
        for (int u = 0; u < 8; ++u)
            myc += (buf[u].x > thr) + (buf[u].y > thr) +
                   (buf[u].z > thr) + (buf[u].w > thr);
        int inc = myc;
        #pragma unroll
        for (int o = 1; o < 64; o <<= 1) {
            int y = __shfl_up(inc, o, 64);
            if (lane >= o) inc += y;
        }
        int base = cnt + inc - myc;
        cnt += __shfl(inc, 63, 64);
        #pragma unroll
        for (int u = 0; u < 8; ++u) {
            float xs[4] = {buf[u].x, buf[u].y, buf[u].z, buf[u].w};
            #pragma unroll
            for (int q = 0; q < 4; ++q) {
                if (xs[q] > thr) {
                    if (base < CAP) {
                        vals[base] = xs[q];
                        idxs[base] = (uint16_t)((((c0 + u) * 64 + lane) << 2) + q);
                    }
                    ++base;
                }
            }
        }
    }
    if (cnt < KSEL || cnt > CAP) return wave_slow_kl(tg, s, NF4 * 256);

    // keys to regs + EARLY student gather (vmcnt loads drain under bisection)
    uint32_t key[NSLOT];
    float svc[NSLOT];
    #pragma unroll
    for (int j = 0; j < NSLOT; ++j) {
        int p = lane + j * 64;
        bool v = p < cnt;
        key[j] = v ? fkey(vals[p]) : 0u;
        svc[j] = v ? s[(int)idxs[p]] : 0.f;
    }
    uint32_t kmx = 0u, kmn = 0xFFFFFFFFu;
    #pragma unroll
    for (int j = 0; j < NSLOT; ++j) {
        uint32_t k = key[j];
        kmx = k > kmx ? k : kmx;
        if (k) kmn = k < kmn ? k : kmn;
    }
    #pragma unroll
    for (int o = 32; o > 0; o >>= 1) {
        uint32_t a = __shfl_xor(kmx, o, 64); kmx = a > kmx ? a : kmx;
        uint32_t b = __shfl_xor(kmn, o, 64); kmn = b < kmn ? b : kmn;
    }
    const float tmax = keyf(kmx);

    uint32_t lo = kmn - 1u, hi = kmx, tauhi = kmx;
    int cl = cnt, ch = 0, cut = -1;
    bool exact = false;
    for (int it = 0; it < 80; ++it) {
        uint32_t span = hi - lo;
        if (span <= 1u) break;
        uint32_t mid;
        if (!(it & 1)) {  // false position on empirical CDF
            uint64_t st = (uint64_t)span * (uint32_t)(cl - KSEL) / (uint32_t)(cl - ch);
            if (st < 1) st = 1;
            if (st > span - 1) st = span - 1;
            mid = lo + (uint32_t)st;
        } else mid = lo + (span >> 1);
        int c = 0;
        #pragma unroll
        for (int j = 0; j < NSLOT; ++j) c += (key[j] > mid);
        c = wave_sumi(c);
        if (c == KSEL) { tauhi = mid; exact = true; break; }
        if (c > KSEL) { lo = mid; cl = c; } else { hi = mid; ch = c; }
    }
    if (!exact) {
        tauhi = hi;
        const int nT = KSEL - ch, nTie = cl - ch;
        if (nT >= nTie) cut = 0x7FFFFFFF;
        else {  // lowest-index tie-break; idx re-read from LDS (rare path)
            int l = -1, h = 8191;
            while (h - l > 1) {
                int m = (l + h) >> 1;
                int c = 0;
                #pragma unroll
                for (int j = 0; j < NSLOT; ++j) {
                    int p = lane + j * 64;
                    c += (key[j] == tauhi && p < cnt && (int)idxs[p] <= m);
                }
                c = wave_sumi(c);
                if (c >= nT) h = m; else l = m;
            }
            cut = h;
        }
    }

    uint32_t selm = 0u;
    if (cut == -1) {
        #pragma unroll
        for (int j = 0; j < NSLOT; ++j) selm |= (key[j] > tauhi ? 1u : 0u) << j;
    } else if (cut == 0x7FFFFFFF) {
        #pragma unroll
        for (int j = 0; j < NSLOT; ++j) selm |= (key[j] >= tauhi ? 1u : 0u) << j;
    } else {
        #pragma unroll
        for (int j = 0; j < NSLOT; ++j) {
            int p = lane + j * 64;
            bool sj = (key[j] > tauhi) ||
                      (key[j] == tauhi && p < cnt && (int)idxs[p] <= cut);
            selm |= (sj ? 1u : 0u) << j;
        }
    }

    float St = 0.f, Stt = 0.f, Sts = 0.f, sm = -FLT_MAX;
    #pragma unroll
    for (int j = 0; j < NSLOT; ++j) {
        if (selm & (1u << j)) {
            float tv = keyf(key[j]);
            float e = __expf(tv - tmax);
            St += e; Stt += e * tv; Sts += e * svc[j];
            sm = fmaxf(sm, svc[j]);
        }
    }
    #pragma unroll
    for (int o = 32; o > 0; o >>= 1) {
        St  += __shfl_xor(St,  o, 64);
        Stt += __shfl_xor(Stt, o, 64);
        Sts += __shfl_xor(Sts, o, 64);
        sm = fmaxf(sm, __shfl_xor(sm, o, 64));
    }
    float Ss = 0.f;
    #pragma unroll
    for (int j = 0; j < NSLOT; ++j)
        if (selm & (1u << j)) Ss += __expf(svc[j] - sm);
    Ss = wave_sumf(Ss);
    if (lane == 0)
        return (Stt - Sts) / St - tmax - __logf(St) + sm + __logf(Ss);
    return 0.f;
}

// Exact top-KSEL + KL on dense register-resident keys with student prefetch.
template <int NS, class IdxF>
__device__ float select_accum(uint32_t (&key)[NS], IdxF idxOf, const float* svp) {
    const int lane = threadIdx.x & 63;
    uint32_t kmx = 0u, kmn = 0xFFFFFFFFu;
    #pragma unroll
    for (int j = 0; j < NS; ++j) {
        uint32_t k = key[j];
        kmx = k > kmx ? k : kmx;
        kmn = k < kmn ? k : kmn;
    }
    #pragma unroll
    for (int o = 32; o > 0; o >>= 1) {
        uint32_t a = __shfl_xor(kmx, o, 64); kmx = a > kmx ? a : kmx;
        uint32_t b = __shfl_xor(kmn, o, 64); kmn = b < kmn ? b : kmn;
    }
    const float tmax = keyf(kmx);

    uint32_t lo = kmn - 1u, hi = kmx, tauhi = kmx;
    int cl = NS * 64, ch = 0, cut = -1;
    bool exact = false;
    for (int it = 0; it < 80; ++it) {
        uint32_t span = hi - lo;
        if (span <= 1u) break;
        uint32_t mid;
        if (!(it & 1)) {
            uint64_t st = (uint64_t)span * (uint32_t)(cl - KSEL) / (uint32_t)(cl - ch);
            if (st < 1) st = 1;
            if (st > span - 1) st = span - 1;
            mid = lo + (uint32_t)st;
        } else mid = lo + (span >> 1);
        int c = 0;
        #pragma unroll
        for (int j = 0; j < NS; ++j) c += (key[j] > mid);
        c = wave_sumi(c);
        if (c == KSEL) { tauhi = mid; exact = true; break; }
        if (c > KSEL) { lo = mid; cl = c; } else { hi = mid; ch = c; }
    }
    if (!exact) {
        tauhi = hi;
        const int nT = KSEL - ch, nTie = cl - ch;
        if (nT >= nTie) cut = 0x7FFFFFFF;
        else {
            int l = -1, h = NS * 64 - 1;
            while (h - l > 1) {
                int m = (l + h) >> 1;
                int c = 0;
                #pragma unroll
                for (int j = 0; j < NS; ++j)
                    c += (key[j] == tauhi && idxOf(j) <= m);
                c = wave_sumi(c);
                if (c >= nT) h = m; else l = m;
            }
            cut = h;
        }
    }

    float St = 0.f, Stt = 0.f, Sts = 0.f, sm = -FLT_MAX;
    #pragma unroll
    for (int j = 0; j < NS; ++j) {
        uint32_t kj = key[j];
        bool sj = (kj > tauhi) || (kj == tauhi && idxOf(j) <= cut);
        if (sj) {
            float tv = keyf(kj);
            float e = __expf(tv - tmax);
            St += e; Stt += e * tv; Sts += e * svp[j];
            sm = fmaxf(sm, svp[j]);
        }
    }
    #pragma unroll
    for (int o = 32; o > 0; o >>= 1) {
        St  += __shfl_xor(St,  o, 64);
        Stt += __shfl_xor(Stt, o, 64);
        Sts += __shfl_xor(Sts, o, 64);
        sm = fmaxf(sm, __shfl_xor(sm, o, 64));
    }
    float Ss = 0.f;
    #pragma unroll
    for (int j = 0; j < NS; ++j) {
        uint32_t kj = key[j];
        bool sj = (kj > tauhi) || (kj == tauhi && idxOf(j) <= cut);
        if (sj) Ss += __expf(svp[j] - sm);
    }
    Ss = wave_sumf(Ss);
    const int lane0 = lane;
    if (lane0 == 0)
        return (Stt - Sts) / St - tmax - __logf(St) + sm + __logf(Ss);
    return 0.f;
}

// mid groups (C = NJ*64): whole group + student prefetched to registers
template <int NJ>
__device__ float mid_wave(const float* __restrict__ t, const float* __restrict__ s) {
    const int lane = threadIdx.x & 63;
    const float4* t4 = (const float4*)t;
    const float4* s4 = (const float4*)s;
    uint32_t key[NJ];
    float svp[NJ];
    #pragma unroll
    for (int c = 0; c < NJ / 4; ++c) {
        float4 x = t4[lane + c * 64];
        float4 y = s4[lane + c * 64];
        key[4 * c + 0] = fkey(x.x); key[4 * c + 1] = fkey(x.y);
        key[4 * c + 2] = fkey(x.z); key[4 * c + 3] = fkey(x.w);
        svp[4 * c + 0] = y.x; svp[4 * c + 1] = y.y;
        svp[4 * c + 2] = y.z; svp[4 * c + 3] = y.w;
    }
    auto idxOf = [&](int j) { return ((lane + (j >> 2) * 64) << 2) + (j & 3); };
    return select_accum<NJ>(key, idxOf, svp);
}

// tiny groups (k == C <= 256): whole-group softmax; returns kl on lane 0
__device__ float tiny_group(const float* __restrict__ t, const float* __restrict__ s,
                            int Cg) {
    const int lane = threadIdx.x & 63;
    float St = 0.f, Stt = 0.f, Sts = 0.f, m = -FLT_MAX, l = 0.f;
    float tv[4], svv[4];
    #pragma unroll
    for (int q = 0; q < 4; ++q) {
        int i = lane + q * 64;
        bool va = i < Cg;
        tv[q] = va ? t[i] : -FLT_MAX;
        svv[q] = va ? s[i] : 0.f;
    }
    float mx = -FLT_MAX;
    #pragma unroll
    for (int q = 0; q < 4; ++q) mx = fmaxf(mx, tv[q]);
    mx = wave_maxf(mx);
    #pragma unroll
    for (int q = 0; q < 4; ++q) {
        if (lane + q * 64 < Cg) {
            float e = __expf(tv[q] - mx);
            St += e; Stt += e * tv[q]; Sts += e * svv[q];
            float x = svv[q];
            if (x > m) { l = l * __expf(m - x) + 1.f; m = x; }
            else       { l += __expf(x - m); }
        }
    }
    #pragma unroll
    for (int o = 32; o > 0; o >>= 1) {
        St  += __shfl_xor(St,  o, 64);
        Stt += __shfl_xor(Stt, o, 64);
        Sts += __shfl_xor(Sts, o, 64);
        float m2 = __shfl_xor(m, o, 64);
        float l2 = __shfl_xor(l, o, 64);
        lse_merge(m, l, m2, l2);
    }
    if (lane == 0)
        return (Stt - Sts) / St - mx - __logf(St) + m + __logf(l);
    return 0.f;
}

// 256 threads = 4 INDEPENDENT waves (no __syncthreads anywhere): wave w
// handles group-set w of this block's row. 4 blocks/CU -> 16 waves/CU.
__global__ __launch_bounds__(256, 4) void kd_all(const float* __restrict__ sL,
                                                 const float* __restrict__ tL,
                                                 float* __restrict__ partial) {
    __shared__ float    vals[2][CAP];   // 10 KiB  (waves 0,1)
    __shared__ uint16_t idxs[2][CAP];   // 5 KiB
    const int row = blockIdx.x;
    const int w = threadIdx.x >> 6;
    const float* tr = tL + (size_t)row * TOTAL;
    const float* sr = sL + (size_t)row * TOTAL;

    float kl = 0.f;
    switch (w) {
    case 0: kl = big_wave<32>(tr,        sr,        1.10f, vals[0], idxs[0]); break;
    case 1: kl = big_wave<16>(tr + 8192, sr + 8192, 0.60f, vals[1], idxs[1]); break;
    case 2:
        kl  = mid_wave<32>(tr + 12288, sr + 12288);   // C=2048
        kl += mid_wave<16>(tr + 14336, sr + 14336);   // C=1024
        break;
    default:
        kl  = mid_wave<8>(tr + 15360, sr + 15360);    // C=512
        kl += tiny_group(tr + 15872, sr + 15872, 256);
        kl += tiny_group(tr + 16128, sr + 16128, 128);
        kl += tiny_group(tr + 16256, sr + 16256, 64);
        kl += tiny_group(tr + 16320, sr + 16320, 32);
        kl += tiny_group(tr + 16352, sr + 16352, 16);
        break;
    }
    if ((threadIdx.x & 63) == 0)
        atomicAdd(&partial[(row + w * 37) & (NBUCKET - 1)], kl * (0.1f / 1024.f));
}

__global__ void zero_ws(float* partial) {
    if (threadIdx.x < NBUCKET) partial[threadIdx.x] = 0.f;
}

__global__ void final_sum(const float* __restrict__ partial, float* __restrict__ out) {
    float v = (threadIdx.x < NBUCKET) ? partial[threadIdx.x] : 0.f;
    #pragma unroll
    for (int o = 32; o > 0; o >>= 1) v += __shfl_down(v, o, 64);
    if (threadIdx.x == 0) out[0] = v;
}

extern "C" void kernel_launch(void* const* d_in, const int* in_sizes, int n_in,
                              void* d_out, int out_size, void* d_ws, size_t ws_size,
                              hipStream_t stream) {
    (void)in_sizes; (void)n_in; (void)ws_size; (void)out_size;
    const float* s = (const float*)d_in[0];
    const float* t = (const float*)d_in[1];
    float* out = (float*)d_out;
    float* ws = (float*)d_ws;

    hipLaunchKernelGGL(zero_ws, dim3(1), dim3(64), 0, stream, ws);
    hipLaunchKernelGGL(kd_all, dim3(1024), dim3(256), 0, stream, s, t, ws);
    hipLaunchKernelGGL(final_sum, dim3(1), dim3(64), 0, stream, ws, out);
}